// Round 3
// baseline (710.337 us; speedup 1.0000x reference)
//
#include <hip/hip_runtime.h>

#define NPTS 262144
#define DIM 64
#define KCODES 1024

// Prep: embS[k][d] = -2*emb[k][d], e2[k] = sum_d emb[k][d]^2  (both in d_ws)
__global__ void vq_prep_kernel(const float* __restrict__ emb,
                               float* __restrict__ embS, float* __restrict__ e2) {
    int k = blockIdx.x * blockDim.x + threadIdx.x;
    if (k < KCODES) {
        const float4* row = reinterpret_cast<const float4*>(emb + k * DIM);
        float4* srow = reinterpret_cast<float4*>(embS + k * DIM);
        float s = 0.f;
#pragma unroll
        for (int j = 0; j < DIM / 4; ++j) {
            float4 v = row[j];
            s = fmaf(v.x, v.x, s);
            s = fmaf(v.y, v.y, s);
            s = fmaf(v.z, v.z, s);
            s = fmaf(v.w, v.w, s);
            float4 sv = make_float4(-2.f * v.x, -2.f * v.y, -2.f * v.z, -2.f * v.w);
            srow[j] = sv;
        }
        e2[k] = s;
    }
}

// Main: one thread per point; x-row in 64 VGPRs; k-loop over all codes.
// embS/e2 rows are wave-uniform -> scalar (SMEM) loads, co-issued with VALU.
// score = e2[k] - 2*x.e  (x^2 const per point, sqrt monotone -> same argmin).
__global__ __launch_bounds__(256, 4) void vq_argmin_kernel(
    const float* __restrict__ x, const float* __restrict__ emb,
    const float* __restrict__ embS, const float* __restrict__ e2,
    float* __restrict__ qout, float* __restrict__ iout) {
    const size_t p = (size_t)blockIdx.x * blockDim.x + threadIdx.x;

    // x row: 64 floats -> 64 VGPRs (one-time load).
    float xr[DIM];
    const float4* xrow = reinterpret_cast<const float4*>(x + p * DIM);
#pragma unroll
    for (int j = 0; j < DIM / 4; ++j) {
        float4 v = xrow[j];
        xr[4 * j + 0] = v.x;
        xr[4 * j + 1] = v.y;
        xr[4 * j + 2] = v.z;
        xr[4 * j + 3] = v.w;
    }

    float best = 3.4e38f;
    int bidx = 0;

    for (int k = 0; k < KCODES; ++k) {
        const float4* erow = reinterpret_cast<const float4*>(embS + k * DIM);
        // a0 starts at e2[k]; 4 sub-accumulators break the fmac latency chain.
        float a0 = e2[k], a1 = 0.f, a2 = 0.f, a3 = 0.f;
#pragma unroll
        for (int j = 0; j < DIM / 4; ++j) {
            float4 ev = erow[j];  // wave-uniform
            a0 = fmaf(xr[4 * j + 0], ev.x, a0);
            a1 = fmaf(xr[4 * j + 1], ev.y, a1);
            a2 = fmaf(xr[4 * j + 2], ev.z, a2);
            a3 = fmaf(xr[4 * j + 3], ev.w, a3);
        }
        float score = (a0 + a1) + (a2 + a3);
        // strict < + ascending k => first-index tie-break (matches jnp.argmin)
        if (score < best) { best = score; bidx = k; }
    }

    // quantized[p][:] = emb[bidx][:]
    const float4* qrow = reinterpret_cast<const float4*>(emb + (size_t)bidx * DIM);
    float4* orow = reinterpret_cast<float4*>(qout + p * DIM);
#pragma unroll
    for (int j = 0; j < DIM / 4; ++j) orow[j] = qrow[j];

    iout[p] = (float)bidx;  // indices output (concatenated after quantized)
}

extern "C" void kernel_launch(void* const* d_in, const int* in_sizes, int n_in,
                              void* d_out, int out_size, void* d_ws, size_t ws_size,
                              hipStream_t stream) {
    const float* x = (const float*)d_in[0];    // [N, D] f32
    const float* emb = (const float*)d_in[1];  // [K, D] f32
    float* qout = (float*)d_out;               // [N, D] f32
    float* iout = (float*)d_out + (size_t)NPTS * DIM;  // [N] indices (as float)
    float* embS = (float*)d_ws;                // [K, D] f32: -2*emb
    float* e2 = embS + (size_t)KCODES * DIM;   // [K] f32

    vq_prep_kernel<<<(KCODES + 255) / 256, 256, 0, stream>>>(emb, embS, e2);
    vq_argmin_kernel<<<NPTS / 256, 256, 0, stream>>>(x, emb, embS, e2, qout, iout);
}

// Round 4
// 698.561 us; speedup vs baseline: 1.0169x; 1.0169x over previous
//
#include <hip/hip_runtime.h>

#define NPTS 262144
#define DIM 64
#define KCODES 1024

// Prep: embS[k][d] = -2*emb[k][d], e2[k] = sum_d emb[k][d]^2  (both in d_ws)
__global__ void vq_prep_kernel(const float* __restrict__ emb,
                               float* __restrict__ embS, float* __restrict__ e2) {
    int k = blockIdx.x * blockDim.x + threadIdx.x;
    if (k < KCODES) {
        const float4* row = reinterpret_cast<const float4*>(emb + k * DIM);
        float4* srow = reinterpret_cast<float4*>(embS + k * DIM);
        float s = 0.f;
#pragma unroll
        for (int j = 0; j < DIM / 4; ++j) {
            float4 v = row[j];
            s = fmaf(v.x, v.x, s);
            s = fmaf(v.y, v.y, s);
            s = fmaf(v.z, v.z, s);
            s = fmaf(v.w, v.w, s);
            srow[j] = make_float4(-2.f * v.x, -2.f * v.y, -2.f * v.z, -2.f * v.w);
        }
        e2[k] = s;
    }
}

// One thread per point. x-row held in 16 NAMED float4s (no array -> no
// alloca -> no scratch demotion; pure SSA values the regalloc keeps in VGPRs).
// embS rows are wave-uniform -> scalar (SMEM) loads co-issued with VALU.
// score = e2[k] - 2*x.e  (x^2 const per point; sqrt monotone -> same argmin).
__global__ __launch_bounds__(256, 4) void vq_argmin_kernel(
    const float* __restrict__ x, const float* __restrict__ emb,
    const float* __restrict__ embS, const float* __restrict__ e2,
    float* __restrict__ qout, float* __restrict__ iout) {
    const size_t p = (size_t)blockIdx.x * blockDim.x + threadIdx.x;

    const float4* xrow = reinterpret_cast<const float4*>(x + p * DIM);
    const float4 x0 = xrow[0], x1 = xrow[1], x2 = xrow[2], x3 = xrow[3];
    const float4 x4 = xrow[4], x5 = xrow[5], x6 = xrow[6], x7 = xrow[7];
    const float4 x8 = xrow[8], x9 = xrow[9], x10 = xrow[10], x11 = xrow[11];
    const float4 x12 = xrow[12], x13 = xrow[13], x14 = xrow[14], x15 = xrow[15];

    float best = 3.4e38f;
    int bidx = 0;

#pragma unroll 2
    for (int k = 0; k < KCODES; ++k) {
        const float4* erow = reinterpret_cast<const float4*>(embS + k * DIM);
        float a0 = e2[k], a1 = 0.f, a2 = 0.f, a3 = 0.f;
#define VQ_STEP(i, xi)                                   \
        {                                                \
            float4 ev = erow[i];                         \
            a0 = fmaf((xi).x, ev.x, a0);                 \
            a1 = fmaf((xi).y, ev.y, a1);                 \
            a2 = fmaf((xi).z, ev.z, a2);                 \
            a3 = fmaf((xi).w, ev.w, a3);                 \
        }
        VQ_STEP(0, x0)   VQ_STEP(1, x1)   VQ_STEP(2, x2)   VQ_STEP(3, x3)
        VQ_STEP(4, x4)   VQ_STEP(5, x5)   VQ_STEP(6, x6)   VQ_STEP(7, x7)
        VQ_STEP(8, x8)   VQ_STEP(9, x9)   VQ_STEP(10, x10) VQ_STEP(11, x11)
        VQ_STEP(12, x12) VQ_STEP(13, x13) VQ_STEP(14, x14) VQ_STEP(15, x15)
#undef VQ_STEP
        float score = (a0 + a1) + (a2 + a3);
        // strict < + ascending k => first-index tie-break (matches jnp.argmin)
        if (score < best) { best = score; bidx = k; }
    }

    // quantized[p][:] = emb[bidx][:]
    const float4* qrow = reinterpret_cast<const float4*>(emb + (size_t)bidx * DIM);
    float4* orow = reinterpret_cast<float4*>(qout + p * DIM);
#pragma unroll
    for (int j = 0; j < DIM / 4; ++j) orow[j] = qrow[j];

    iout[p] = (float)bidx;  // indices output (concatenated after quantized)
}

extern "C" void kernel_launch(void* const* d_in, const int* in_sizes, int n_in,
                              void* d_out, int out_size, void* d_ws, size_t ws_size,
                              hipStream_t stream) {
    const float* x = (const float*)d_in[0];    // [N, D] f32
    const float* emb = (const float*)d_in[1];  // [K, D] f32
    float* qout = (float*)d_out;               // [N, D] f32
    float* iout = (float*)d_out + (size_t)NPTS * DIM;  // [N] indices (as float)
    float* embS = (float*)d_ws;                // [K, D] f32: -2*emb
    float* e2 = embS + (size_t)KCODES * DIM;   // [K] f32

    vq_prep_kernel<<<(KCODES + 255) / 256, 256, 0, stream>>>(emb, embS, e2);
    vq_argmin_kernel<<<NPTS / 256, 256, 0, stream>>>(x, emb, embS, e2, qout, iout);
}

// Round 7
// 352.169 us; speedup vs baseline: 2.0170x; 1.9836x over previous
//
#include <hip/hip_runtime.h>

#define NPTS 262144
#define DIM 64
#define KCODES 1024

typedef short bf16x8 __attribute__((ext_vector_type(8)));
typedef float f32x4 __attribute__((ext_vector_type(4)));
typedef short short8 __attribute__((ext_vector_type(8)));

// ---------- ws layout ----------
// gtile: tiled bf16 splits of eS=-2*emb: 64 kc-tiles * 3 splits * 2 chunks * 64 granules * 16B = 393216 B
// e2g:   1024 f32 at +393216
// candidate pairs are packed into iout (d_out indices region): u32 = i1 | (i2<<10)
#define GTILE_BYTES 393216
#define E2_OFF (GTILE_BYTES)

__device__ __forceinline__ unsigned short bf16_rne(float v) {
    unsigned int u = __float_as_uint(v);
    return (unsigned short)((u + 0x7FFFu + ((u >> 16) & 1u)) >> 16);
}
__device__ __forceinline__ float bf16_to_f32(unsigned short h) {
    return __uint_as_float(((unsigned int)h) << 16);
}

// e2[k] = sum emb[k][d]^2 — EXACT same accumulation as rounds 2-4 (passed absmax=0)
__global__ void vq_e2_kernel(const float* __restrict__ emb, float* __restrict__ e2) {
    int k = blockIdx.x * blockDim.x + threadIdx.x;
    if (k < KCODES) {
        const float4* row = reinterpret_cast<const float4*>(emb + k * DIM);
        float s = 0.f;
#pragma unroll
        for (int j = 0; j < DIM / 4; ++j) {
            float4 v = row[j];
            s = fmaf(v.x, v.x, s);
            s = fmaf(v.y, v.y, s);
            s = fmaf(v.z, v.z, s);
            s = fmaf(v.w, v.w, s);
        }
        e2[k] = s;
    }
}

// Tile eS=-2*emb into MFMA-granule order, 3-way bf16 split.
// granule t -> (kc = t/384, s = (t%384)/128, chunk = (t%128)/64, l = t%64)
// lane semantics: code16 = l&15, hi = l>>4; elements = eS[kc*16+code16][chunk*32+hi*8 .. +7]
__global__ void vq_tile_kernel(const float* __restrict__ emb, unsigned short* __restrict__ gtile) {
    int t = blockIdx.x * blockDim.x + threadIdx.x;
    if (t >= 64 * 3 * 2 * 64) return;
    int kc = t / 384;
    int r = t % 384;
    int s = r / 128;
    int r2 = r % 128;
    int chunk = r2 / 64;
    int l = r2 % 64;
    int code = kc * 16 + (l & 15);
    int dim0 = chunk * 32 + (l >> 4) * 8;
    const float* src = emb + code * DIM + dim0;
    short8 out;
#pragma unroll
    for (int e = 0; e < 8; ++e) {
        float v = -2.f * src[e];
        unsigned short hs = bf16_rne(v);
        float rr = v - bf16_to_f32(hs);
        unsigned short ms = bf16_rne(rr);
        float rr2 = rr - bf16_to_f32(ms);
        unsigned short ls = bf16_rne(rr2);
        out[e] = (short)((s == 0) ? hs : ((s == 1) ? ms : ls));
    }
    *reinterpret_cast<short8*>(gtile + (size_t)t * 8) = out;
}

// Main: 256 thr = 4 waves; wave owns 32 points (2 MFMA point-tiles).
// C-init = e2 (per-code), accumulate 6 split-pair MFMAs (-2 folded into eS splits)
// -> C = e2 - 2*x.e. Track per-point top-2 in regs; write packed candidate pair.
__global__ __launch_bounds__(256, 2) void vq_mfma_kernel(
    const float* __restrict__ x, const unsigned short* __restrict__ gtile,
    const float* __restrict__ e2g, float* __restrict__ candout) {
    __shared__ __align__(16) unsigned short etile[24576];  // 48 KB
    __shared__ float e2s[128];

    const int tid = threadIdx.x;
    const int lane = tid & 63;
    const int wid = tid >> 6;
    const int ptbase = blockIdx.x * 128 + wid * 32;
    const int c16 = lane & 15;   // A-row / B-col / C-col index within tile
    const int hi = lane >> 4;    // k-subblock / C row group

    // ---- A-prep: load f32 x rows, split to bf16x8 frags in-register ----
    // frag (T, split, chunk): row = ptbase + T*16 + (lane&15), dims chunk*32 + hi*8 + e
    bf16x8 ah[2][2], am[2][2], al[2][2];
#pragma unroll
    for (int T = 0; T < 2; ++T) {
#pragma unroll
        for (int c = 0; c < 2; ++c) {
            const float* src = x + (size_t)(ptbase + T * 16 + c16) * DIM + c * 32 + hi * 8;
            float4 f0 = *reinterpret_cast<const float4*>(src);
            float4 f1 = *reinterpret_cast<const float4*>(src + 4);
            float va[8] = {f0.x, f0.y, f0.z, f0.w, f1.x, f1.y, f1.z, f1.w};
            bf16x8 vh, vm, vl;
#pragma unroll
            for (int e = 0; e < 8; ++e) {
                float v = va[e];
                unsigned short hs = bf16_rne(v);
                float rr = v - bf16_to_f32(hs);
                unsigned short ms = bf16_rne(rr);
                float rr2 = rr - bf16_to_f32(ms);
                unsigned short ls = bf16_rne(rr2);
                vh[e] = (short)hs; vm[e] = (short)ms; vl[e] = (short)ls;
            }
            ah[T][c] = vh; am[T][c] = vm; al[T][c] = vl;
        }
    }

    float b1[2][4], b2[2][4];
    int i1[2][4], i2[2][4];
#pragma unroll
    for (int T = 0; T < 2; ++T)
#pragma unroll
        for (int r = 0; r < 4; ++r) { b1[T][r] = 3.4e38f; b2[T][r] = 3.4e38f; i1[T][r] = 0; i2[T][r] = 0; }

    for (int R = 0; R < 8; ++R) {  // 128 codes per round
        // ---- stage 48KB tile + 128 e2 ----
        const bf16x8* g8 = reinterpret_cast<const bf16x8*>(gtile) + R * 3072;
        bf16x8* l8 = reinterpret_cast<bf16x8*>(etile);
#pragma unroll
        for (int j = 0; j < 12; ++j) l8[tid + j * 256] = g8[tid + j * 256];
        if (tid < 128) e2s[tid] = e2g[R * 128 + tid];
        __syncthreads();

#pragma unroll
        for (int kcL = 0; kcL < 8; ++kcL) {
            const int code_c = R * 128 + kcL * 16 + c16;
            const float e2v = e2s[kcL * 16 + c16];
            f32x4 c0[2], c1[2];  // per-T, per-k-chunk accumulator chains
#pragma unroll
            for (int T = 0; T < 2; ++T) {
                c0[T] = (f32x4){e2v, e2v, e2v, e2v};
                c1[T] = (f32x4){0.f, 0.f, 0.f, 0.f};
            }
            // B frags: (split es, chunk c) at granule block ((kcL*3+es)*2+c)
#pragma unroll
            for (int es = 0; es < 3; ++es) {
                const bf16x8* fb0 = reinterpret_cast<const bf16x8*>(etile + ((kcL * 3 + es) * 2 + 0) * 512);
                const bf16x8* fb1 = reinterpret_cast<const bf16x8*>(etile + ((kcL * 3 + es) * 2 + 1) * 512);
                bf16x8 bC0 = fb0[lane];
                bf16x8 bC1 = fb1[lane];
                if (es == 0) {  // A-splits h,m,l vs B-split h
#pragma unroll
                    for (int T = 0; T < 2; ++T) {
                        c0[T] = __builtin_amdgcn_mfma_f32_16x16x32_bf16(ah[T][0], bC0, c0[T], 0, 0, 0);
                        c1[T] = __builtin_amdgcn_mfma_f32_16x16x32_bf16(ah[T][1], bC1, c1[T], 0, 0, 0);
                        c0[T] = __builtin_amdgcn_mfma_f32_16x16x32_bf16(am[T][0], bC0, c0[T], 0, 0, 0);
                        c1[T] = __builtin_amdgcn_mfma_f32_16x16x32_bf16(am[T][1], bC1, c1[T], 0, 0, 0);
                        c0[T] = __builtin_amdgcn_mfma_f32_16x16x32_bf16(al[T][0], bC0, c0[T], 0, 0, 0);
                        c1[T] = __builtin_amdgcn_mfma_f32_16x16x32_bf16(al[T][1], bC1, c1[T], 0, 0, 0);
                    }
                } else if (es == 1) {  // A-splits h,m vs B-split m
#pragma unroll
                    for (int T = 0; T < 2; ++T) {
                        c0[T] = __builtin_amdgcn_mfma_f32_16x16x32_bf16(ah[T][0], bC0, c0[T], 0, 0, 0);
                        c1[T] = __builtin_amdgcn_mfma_f32_16x16x32_bf16(ah[T][1], bC1, c1[T], 0, 0, 0);
                        c0[T] = __builtin_amdgcn_mfma_f32_16x16x32_bf16(am[T][0], bC0, c0[T], 0, 0, 0);
                        c1[T] = __builtin_amdgcn_mfma_f32_16x16x32_bf16(am[T][1], bC1, c1[T], 0, 0, 0);
                    }
                } else {  // A-split h vs B-split l
#pragma unroll
                    for (int T = 0; T < 2; ++T) {
                        c0[T] = __builtin_amdgcn_mfma_f32_16x16x32_bf16(ah[T][0], bC0, c0[T], 0, 0, 0);
                        c1[T] = __builtin_amdgcn_mfma_f32_16x16x32_bf16(ah[T][1], bC1, c1[T], 0, 0, 0);
                    }
                }
            }
            // top-2 update: lane holds C rows (hi*4+r) = points, col c16 = code
#pragma unroll
            for (int T = 0; T < 2; ++T) {
#pragma unroll
                for (int r = 0; r < 4; ++r) {
                    float s = c0[T][r] + c1[T][r];
                    bool lt1 = s < b1[T][r];
                    bool lt2 = s < b2[T][r];
                    i2[T][r] = lt1 ? i1[T][r] : (lt2 ? code_c : i2[T][r]);
                    b2[T][r] = lt1 ? b1[T][r] : (lt2 ? s : b2[T][r]);
                    i1[T][r] = lt1 ? code_c : i1[T][r];
                    b1[T][r] = lt1 ? s : b1[T][r];
                }
            }
        }
        __syncthreads();
    }

    // ---- merge top-2 across the 16 lanes of each row-group (masks 1,2,4,8) ----
#pragma unroll
    for (int T = 0; T < 2; ++T) {
#pragma unroll
        for (int r = 0; r < 4; ++r) {
#pragma unroll
            for (int mask = 1; mask <= 8; mask <<= 1) {
                float q1 = __shfl_xor(b1[T][r], mask);
                int qi1 = __shfl_xor(i1[T][r], mask);
                float q2 = __shfl_xor(b2[T][r], mask);
                int qi2 = __shfl_xor(i2[T][r], mask);
                bool qbest = (q1 < b1[T][r]) || (q1 == b1[T][r] && qi1 < i1[T][r]);
                float c2a = qbest ? b1[T][r] : b2[T][r];
                int c2ai = qbest ? i1[T][r] : i2[T][r];
                float c2b = qbest ? q2 : q1;
                int c2bi = qbest ? qi2 : qi1;
                bool bsec = (c2b < c2a) || (c2b == c2a && c2bi < c2ai);
                b1[T][r] = qbest ? q1 : b1[T][r];
                i1[T][r] = qbest ? qi1 : i1[T][r];
                b2[T][r] = bsec ? c2b : c2a;
                i2[T][r] = bsec ? c2bi : c2ai;
            }
        }
    }
    if (c16 == 0) {  // one writer per 16-lane group: lanes 0,16,32,48
#pragma unroll
        for (int T = 0; T < 2; ++T)
#pragma unroll
            for (int r = 0; r < 4; ++r) {
                unsigned int packed = (unsigned int)i1[T][r] | ((unsigned int)i2[T][r] << 10);
                candout[ptbase + T * 16 + hi * 4 + r] = __uint_as_float(packed);
            }
    }
}

// Rescue: exact fp32 re-score of the two candidates (identical accumulation
// pattern to the rounds-2-4 kernel that passed absmax=0), pick, emit outputs.
__global__ void vq_rescue_kernel(const float* __restrict__ x, const float* __restrict__ emb,
                                 const float* __restrict__ e2,
                                 float* __restrict__ qout, float* __restrict__ iout) {
    const size_t p = (size_t)blockIdx.x * blockDim.x + threadIdx.x;
    unsigned int cw = __float_as_uint(iout[p]);  // packed candidates from vq_mfma_kernel
    int ca = (int)(cw & 1023u);
    int cb = (int)((cw >> 10) & 1023u);
    const float4* xrow = reinterpret_cast<const float4*>(x + p * DIM);
    const float4* ea = reinterpret_cast<const float4*>(emb + (size_t)ca * DIM);
    const float4* eb = reinterpret_cast<const float4*>(emb + (size_t)cb * DIM);
    float a0 = 0.f, a1 = 0.f, a2 = 0.f, a3 = 0.f;
    float d0 = 0.f, d1 = 0.f, d2 = 0.f, d3 = 0.f;
#pragma unroll
    for (int j = 0; j < DIM / 4; ++j) {
        float4 xv = xrow[j];
        float4 va = ea[j];
        float4 vb = eb[j];
        a0 = fmaf(xv.x, va.x, a0);
        a1 = fmaf(xv.y, va.y, a1);
        a2 = fmaf(xv.z, va.z, a2);
        a3 = fmaf(xv.w, va.w, a3);
        d0 = fmaf(xv.x, vb.x, d0);
        d1 = fmaf(xv.y, vb.y, d1);
        d2 = fmaf(xv.z, vb.z, d2);
        d3 = fmaf(xv.w, vb.w, d3);
    }
    float sa = fmaf(-2.f, (a0 + a1) + (a2 + a3), e2[ca]);
    float sb = fmaf(-2.f, (d0 + d1) + (d2 + d3), e2[cb]);
    bool bwins = (sb < sa) || (sb == sa && cb < ca);
    int win = bwins ? cb : ca;

    const float4* qrow = reinterpret_cast<const float4*>(emb + (size_t)win * DIM);
    float4* orow = reinterpret_cast<float4*>(qout + p * DIM);
#pragma unroll
    for (int j = 0; j < DIM / 4; ++j) orow[j] = qrow[j];
    iout[p] = (float)win;
}

extern "C" void kernel_launch(void* const* d_in, const int* in_sizes, int n_in,
                              void* d_out, int out_size, void* d_ws, size_t ws_size,
                              hipStream_t stream) {
    const float* x = (const float*)d_in[0];    // [N, D] f32
    const float* emb = (const float*)d_in[1];  // [K, D] f32
    float* qout = (float*)d_out;               // [N, D] f32
    float* iout = (float*)d_out + (size_t)NPTS * DIM;  // [N] indices (as float)

    unsigned short* gtile = (unsigned short*)d_ws;
    float* e2g = (float*)((char*)d_ws + E2_OFF);

    vq_e2_kernel<<<(KCODES + 255) / 256, 256, 0, stream>>>(emb, e2g);
    vq_tile_kernel<<<(64 * 3 * 2 * 64 + 255) / 256, 256, 0, stream>>>(emb, gtile);
    vq_mfma_kernel<<<NPTS / 128, 256, 0, stream>>>(x, gtile, e2g, iout);
    vq_rescue_kernel<<<NPTS / 256, 256, 0, stream>>>(x, emb, e2g, qout, iout);
}